// Round 4
// baseline (237.652 us; speedup 1.0000x reference)
//
#include <hip/hip_runtime.h>
#include <hip/hip_bf16.h>

#define N_NODES 100000
#define E_NUM   1600000
#define IN_DIM  128
#define HID     64
#define NCLS    40
#define NBUCK   782      // ceil(N_NODES/128); bucket b owns nodes [b*128, b*128+128)
#define TILE_E  8192     // big tiles: bucket runs of ~10 slots -> write locality
#define NTILE   196      // ceil(E_NUM / TILE_E)
#define BCAP    3072     // per-bucket capacity incl. pad-to-8
#define ZROW    N_NODES  // sentinel node whose H row is all zeros
#define NTILES_M 6250    // N_NODES / 16
#define IN_BLOCKS 1563   // ceil(NTILES_M / 4)
#define PREP_BLKS 46
#define SSEG    1536     // LDS srcs-segment capacity per gather block

typedef __attribute__((ext_vector_type(8))) short bf16x8;
typedef __attribute__((ext_vector_type(4))) float f32x4;

// bf16 helpers
static __device__ __forceinline__ float bflo(unsigned u) {
    return __uint_as_float(u << 16);
}
static __device__ __forceinline__ float bfhi(unsigned u) {
    return __uint_as_float(u & 0xFFFF0000u);
}
static __device__ __forceinline__ unsigned short f2bf(float f) {
    unsigned u = __float_as_uint(f);
    u += 0x7FFFu + ((u >> 16) & 1u);     // round-to-nearest-even
    return (unsigned short)(u >> 16);
}
static __device__ __forceinline__ unsigned pack2bf(float lo, float hi) {
    return (unsigned)f2bf(lo) | ((unsigned)f2bf(hi) << 16);
}

// ---- K1: blocks 0..195 partition edges into buckets (batched loads);
//          blocks 196..241 pre-swizzle weights + zero H sentinel rows.
__global__ __launch_bounds__(256) void k_part_prep(
    const int* __restrict__ ei, int* __restrict__ cursor, int* __restrict__ pairs,
    const float* __restrict__ Win, const float* __restrict__ Wl,
    const float* __restrict__ Wc, unsigned* __restrict__ pWin,
    unsigned* __restrict__ pWl, unsigned* __restrict__ pWc,
    unsigned short* __restrict__ H0, unsigned short* __restrict__ H1)
{
    __shared__ int lh[NBUCK];
    __shared__ int lbase[NBUCK];
    __shared__ int lcnt[NBUCK];
    const int t = threadIdx.x;

    if (blockIdx.x < NTILE) {
        for (int i = t; i < NBUCK; i += 256) { lh[i] = 0; lcnt[i] = 0; }
        __syncthreads();
        const int e0 = blockIdx.x * TILE_E;
        // pass 1: histogram — batch 8 loads ahead of the LDS atomics
        #pragma unroll
        for (int k = 0; k < TILE_E; k += 2048) {
            int d[8];
            #pragma unroll
            for (int j = 0; j < 8; ++j) {
                const int e = e0 + k + j * 256 + t;
                d[j] = (e < E_NUM) ? ei[E_NUM + e] : -1;
            }
            #pragma unroll
            for (int j = 0; j < 8; ++j)
                if (d[j] >= 0) atomicAdd(&lh[d[j] >> 7], 1);
        }
        __syncthreads();
        for (int i = t; i < NBUCK; i += 256)
            lbase[i] = lh[i] ? atomicAdd(&cursor[i], lh[i]) : 0;
        __syncthreads();
        // pass 2: scatter — batch 4 edges (8 loads) ahead of atomic+store
        #pragma unroll
        for (int k = 0; k < TILE_E; k += 1024) {
            int s[4], d[4];
            #pragma unroll
            for (int j = 0; j < 4; ++j) {
                const int e = e0 + k + j * 256 + t;
                if (e < E_NUM) { s[j] = ei[e]; d[j] = ei[E_NUM + e]; }
                else           { s[j] = -1;    d[j] = -1; }
            }
            #pragma unroll
            for (int j = 0; j < 4; ++j) {
                if (d[j] >= 0) {
                    const int bkt = d[j] >> 7;
                    const int r   = lbase[bkt] + atomicAdd(&lcnt[bkt], 1);
                    if (r < BCAP) pairs[bkt * BCAP + r] = (s[j] << 7) | (d[j] & 127);
                }
            }
        }
        return;
    }

    // ---- prep half ----
    const int bi = blockIdx.x - NTILE;
    if (bi == 0 && t < 32) {
        ((unsigned*)(H0 + (size_t)ZROW * HID))[t] = 0;
        ((unsigned*)(H1 + (size_t)ZROW * HID))[t] = 0;
    }
    int i = bi * 256 + t;
    if (i < 4096) {                       // W_in: 4 ntiles x 4 ksteps
        const int nt = i >> 10, ks = (i >> 8) & 3, ln = (i >> 2) & 63, jp = i & 3;
        const int n = nt * 16 + (ln & 15);
        const int k = ks * 32 + (ln >> 4) * 8 + jp * 2;
        pWin[i] = pack2bf(Win[k * HID + n], Win[(k + 1) * HID + n]);
    } else if (i < 10240) {               // 3 layers: 4 ntiles x 2 ksteps each
        int j = i - 4096;
        const int l = j >> 11; j &= 2047;
        const int nt = j >> 9, ks = (j >> 8) & 1, ln = (j >> 2) & 63, jp = j & 3;
        const int n = nt * 16 + (ln & 15);
        const int k = ks * 32 + (ln >> 4) * 8 + jp * 2;
        const float* w = Wl + (size_t)l * HID * HID;
        pWl[i - 4096] = pack2bf(w[k * HID + n], w[(k + 1) * HID + n]);
    } else if (i < 11776) {               // W_cls: 3 ntiles (48 cols, pad) x 2 ks
        const int j = i - 10240;
        const int nt = j >> 9, ks = (j >> 8) & 1, ln = (j >> 2) & 63, jp = j & 3;
        const int n = nt * 16 + (ln & 15);
        const int k = ks * 32 + (ln >> 4) * 8 + jp * 2;
        pWc[j] = (n < NCLS) ? pack2bf(Wc[k * NCLS + n], Wc[(k + 1) * NCLS + n]) : 0u;
    }
}

// ---- K2: blocks 0..781 bsort (per-bucket counting sort -> padded CSR);
//          blocks 782+ input GEMM. They co-run (m114: time = max).
__global__ __launch_bounds__(256) void k_bsort_ingemm(
    const int* __restrict__ cursor, const int* __restrict__ pairs,
    int* __restrict__ srcs, int* __restrict__ row_start, int* __restrict__ row_end,
    const float* __restrict__ x, const unsigned* __restrict__ pWin,
    const float* __restrict__ b, unsigned short* __restrict__ H0)
{
    __shared__ int cnt[128];
    __shared__ int sc[128];
    __shared__ int cur[128];
    const int t = threadIdx.x;

    if (blockIdx.x < NBUCK) {
        const int bk = blockIdx.x;
        const int beg = bk * BCAP;
        const int n_e = min(cursor[bk], BCAP);
        if (t < 128) cnt[t] = 0;
        __syncthreads();
        // count — batch 4 loads ahead of atomics
        for (int i = t; i < n_e; i += 1024) {
            const int p0 = pairs[beg + i];
            const int p1 = (i + 256 < n_e) ? pairs[beg + i + 256] : -1;
            const int p2 = (i + 512 < n_e) ? pairs[beg + i + 512] : -1;
            const int p3 = (i + 768 < n_e) ? pairs[beg + i + 768] : -1;
            atomicAdd(&cnt[p0 & 127], 1);
            if (p1 >= 0) atomicAdd(&cnt[p1 & 127], 1);
            if (p2 >= 0) atomicAdd(&cnt[p2 & 127], 1);
            if (p3 >= 0) atomicAdd(&cnt[p3 & 127], 1);
        }
        __syncthreads();
        if (t < 128) sc[t] = (cnt[t] + 7) & ~7;
        __syncthreads();
        for (int off = 1; off < 128; off <<= 1) {
            int a = (t < 128 && t >= off) ? sc[t - off] : 0;
            __syncthreads();
            if (t < 128) sc[t] += a;
            __syncthreads();
        }
        const int node0 = bk << 7;
        if (t < 128) {
            const int pc = (cnt[t] + 7) & ~7;
            const int ex = sc[t] - pc;
            cur[t] = ex;
            const int node = node0 + t;
            if (node < N_NODES) {
                const int rs = beg + ex;
                row_start[node] = rs;
                row_end  [node] = min(rs + pc, beg + BCAP);
            }
            const int fb = beg + ex + cnt[t];
            const int fe = min(beg + ex + pc, beg + BCAP);
            for (int i = fb; i < fe; ++i) srcs[i] = ZROW;
        }
        __syncthreads();
        // scatter — batch 4 loads
        for (int i = t; i < n_e; i += 1024) {
            const int p0 = pairs[beg + i];
            const int p1 = (i + 256 < n_e) ? pairs[beg + i + 256] : -1;
            const int p2 = (i + 512 < n_e) ? pairs[beg + i + 512] : -1;
            const int p3 = (i + 768 < n_e) ? pairs[beg + i + 768] : -1;
            { const int r = atomicAdd(&cur[p0 & 127], 1); if (r < BCAP) srcs[beg + r] = p0 >> 7; }
            if (p1 >= 0) { const int r = atomicAdd(&cur[p1 & 127], 1); if (r < BCAP) srcs[beg + r] = p1 >> 7; }
            if (p2 >= 0) { const int r = atomicAdd(&cur[p2 & 127], 1); if (r < BCAP) srcs[beg + r] = p2 >> 7; }
            if (p3 >= 0) { const int r = atomicAdd(&cur[p3 & 127], 1); if (r < BCAP) srcs[beg + r] = p3 >> 7; }
        }
        return;
    }

    // ---------------- in_gemm block (MFMA, register-direct) ----------------
    const int blk  = blockIdx.x - NBUCK;
    const int lane = t & 63;
    const int w    = t >> 6;
    const int tile = blk * 4 + w;
    if (tile >= NTILES_M) return;
    const int quad = lane >> 4;
    const int mrow = lane & 15;
    const int gr   = tile * 16 + mrow;            // < 100000 always (N%16==0)
    const float* xr = x + (size_t)gr * IN_DIM;
    const bf16x8* pb = (const bf16x8*)pWin;

    f32x4 acc0 = {0.f, 0.f, 0.f, 0.f};
    f32x4 acc1 = {0.f, 0.f, 0.f, 0.f};
    f32x4 acc2 = {0.f, 0.f, 0.f, 0.f};
    f32x4 acc3 = {0.f, 0.f, 0.f, 0.f};
    #pragma unroll
    for (int ks = 0; ks < 4; ++ks) {
        const float4 v0 = *(const float4*)(xr + ks * 32 + quad * 8);
        const float4 v1 = *(const float4*)(xr + ks * 32 + quad * 8 + 4);
        union { unsigned u[4]; bf16x8 v; } au;
        au.u[0] = pack2bf(v0.x, v0.y);
        au.u[1] = pack2bf(v0.z, v0.w);
        au.u[2] = pack2bf(v1.x, v1.y);
        au.u[3] = pack2bf(v1.z, v1.w);
        acc0 = __builtin_amdgcn_mfma_f32_16x16x32_bf16(au.v, pb[       ks * 64 + lane], acc0, 0, 0, 0);
        acc1 = __builtin_amdgcn_mfma_f32_16x16x32_bf16(au.v, pb[256 +  ks * 64 + lane], acc1, 0, 0, 0);
        acc2 = __builtin_amdgcn_mfma_f32_16x16x32_bf16(au.v, pb[512 +  ks * 64 + lane], acc2, 0, 0, 0);
        acc3 = __builtin_amdgcn_mfma_f32_16x16x32_bf16(au.v, pb[768 +  ks * 64 + lane], acc3, 0, 0, 0);
    }

    const int colg = lane & 15;
    const int nodeb = tile * 16 + quad * 4;
    const float bv0 = b[     colg];
    const float bv1 = b[16 + colg];
    const float bv2 = b[32 + colg];
    const float bv3 = b[48 + colg];
    #pragma unroll
    for (int r = 0; r < 4; ++r) {
        const size_t ob = (size_t)(nodeb + r) * HID;
        H0[ob      + colg] = f2bf(fmaxf(acc0[r] + bv0, 0.f));
        H0[ob + 16 + colg] = f2bf(fmaxf(acc1[r] + bv1, 0.f));
        H0[ob + 32 + colg] = f2bf(fmaxf(acc2[r] + bv2, 0.f));
        H0[ob + 48 + colg] = f2bf(fmaxf(acc3[r] + bv3, 0.f));
    }
}

// ---- shared gather phase: fills sup[16][36] with packed-bf16 U rows -------
// The block's 16 nodes occupy ONE CONTIGUOUS srcs segment (padded CSR in
// node order within a bucket). Stage it into LDS with one coalesced burst;
// per-edge srcs reads become ds_read (~120cy) instead of L2 (~300cy),
// shortening the srcs->gather dependent chain. Global fallback if the
// segment exceeds SSEG (essentially never for this graph).
#define ACC8(u) do { \
        a0 += bflo((u).x); a1 += bfhi((u).x); \
        a2 += bflo((u).y); a3 += bfhi((u).y); \
        a4 += bflo((u).z); a5 += bfhi((u).z); \
        a6 += bflo((u).w); a7 += bfhi((u).w); } while (0)

#define LOADH(s) (*(const uint4*)(Hin + (size_t)(s) * HID + 8 * fl))

#define GBODY(FETCH) \
    for (int nfull = rem >> 4; nfull > 0; --nfull) { \
        const int s0 = FETCH(i     ), s1 = FETCH(i +  2); \
        const int s2 = FETCH(i +  4), s3 = FETCH(i +  6); \
        const int s4 = FETCH(i +  8), s5 = FETCH(i + 10); \
        const int s6 = FETCH(i + 12), s7 = FETCH(i + 14); \
        const uint4 u0 = LOADH(s0); const uint4 u1 = LOADH(s1); \
        const uint4 u2 = LOADH(s2); const uint4 u3 = LOADH(s3); \
        const uint4 u4 = LOADH(s4); const uint4 u5 = LOADH(s5); \
        const uint4 u6 = LOADH(s6); const uint4 u7 = LOADH(s7); \
        ACC8(u0); ACC8(u1); ACC8(u2); ACC8(u3); \
        ACC8(u4); ACC8(u5); ACC8(u6); ACC8(u7); \
        i += 16; \
    } \
    if (rem & 8) { \
        const int s0 = FETCH(i    ), s1 = FETCH(i + 2); \
        const int s2 = FETCH(i + 4), s3 = FETCH(i + 6); \
        const uint4 u0 = LOADH(s0); const uint4 u1 = LOADH(s1); \
        const uint4 u2 = LOADH(s2); const uint4 u3 = LOADH(s3); \
        ACC8(u0); ACC8(u1); ACC8(u2); ACC8(u3); \
    }

static __device__ __forceinline__ void gather_tile(
    const int* __restrict__ row_start, const int* __restrict__ row_end,
    const int* __restrict__ srcs, const unsigned short* __restrict__ Hin,
    unsigned (*sup)[36], int* __restrict__ ssrc, int row0, int t)
{
    // stage the block's contiguous srcs segment into LDS (coalesced)
    const int seg0    = row_start[row0];
    const int seg_len = row_end[row0 + 15] - seg0;
    const bool lds_ok = (seg_len <= SSEG);   // seg_len may be <=0 on overflow clamp
    if (lds_ok) {
        for (int i = t; i < seg_len; i += 256) ssrc[i] = srcs[seg0 + i];
    }
    __syncthreads();

    const int lane = t & 63;
    const int w    = t >> 6;
    const int nd   = lane >> 4;          // node within wave's group of 4
    const int sub  = (lane >> 3) & 1;    // edge-parity subgroup
    const int fl   = lane & 7;           // 16B chunk within 128B row
    const int node = row0 + (w << 2) + nd;

    const int rs = row_start[node];
    int rem = row_end[node] - rs;        // multiple of 8 (padded with ZROW)
    if (rem < 0) rem = 0;                // bucket-overflow clamp can go negative
    int i = rs + sub;

    // self row: independent load, issue before the gather loop
    const uint4 us = LOADH(node);

    float a0 = 0.f, a1 = 0.f, a2 = 0.f, a3 = 0.f;
    float a4 = 0.f, a5 = 0.f, a6 = 0.f, a7 = 0.f;

    if (lds_ok) {
        #define LFETCH(k) ssrc[(k) - seg0]
        GBODY(LFETCH)
        #undef LFETCH
    } else {
        #define GFETCH(k) srcs[(k)]
        GBODY(GFETCH)
        #undef GFETCH
    }

    // reduce across the two edge-parity subgroups (xor lane bit 3)
    a0 += __shfl_xor(a0, 8, 64); a1 += __shfl_xor(a1, 8, 64);
    a2 += __shfl_xor(a2, 8, 64); a3 += __shfl_xor(a3, 8, 64);
    a4 += __shfl_xor(a4, 8, 64); a5 += __shfl_xor(a5, 8, 64);
    a6 += __shfl_xor(a6, 8, 64); a7 += __shfl_xor(a7, 8, 64);

    // add self row (h + agg)
    ACC8(us);

    const int r = (w << 2) + nd;
    if (sub == 0) {
        sup[r][4 * fl    ] = pack2bf(a0, a1);
        sup[r][4 * fl + 1] = pack2bf(a2, a3);
    } else {
        sup[r][4 * fl + 2] = pack2bf(a4, a5);
        sup[r][4 * fl + 3] = pack2bf(a6, a7);
    }
}

// ------- layers 1-2: gather + MFMA layer GEMM, write bf16 Hout -------------
__global__ __launch_bounds__(256) void k_gather_gemm(
    const int* __restrict__ row_start, const int* __restrict__ row_end,
    const int* __restrict__ srcs,
    const unsigned short* __restrict__ Hin, const unsigned* __restrict__ pWl,
    const float* __restrict__ bl, unsigned short* __restrict__ Hout)
{
    __shared__ unsigned sup[16][36];
    __shared__ int ssrc[SSEG];
    const int t = threadIdx.x;
    const int row0 = blockIdx.x * 16;
    gather_tile(row_start, row_end, srcs, Hin, sup, ssrc, row0, t);
    __syncthreads();

    const int lane = t & 63;
    const int w    = t >> 6;
    const int quad = lane >> 4;
    const int m    = lane & 15;
    const bf16x8* pb = (const bf16x8*)pWl;
    f32x4 acc = {0.f, 0.f, 0.f, 0.f};
    #pragma unroll
    for (int ks = 0; ks < 2; ++ks) {
        const bf16x8 a  = *(const bf16x8*)&sup[m][ks * 16 + quad * 4];
        const bf16x8 bb = pb[((w << 1) + ks) * 64 + lane];
        acc = __builtin_amdgcn_mfma_f32_16x16x32_bf16(a, bb, acc, 0, 0, 0);
    }
    const int jc = w * 16 + m;
    const float bv = bl[jc];
    #pragma unroll
    for (int r = 0; r < 4; ++r) {
        const int node = row0 + quad * 4 + r;
        Hout[(size_t)node * HID + jc] = f2bf(fmaxf(acc[r] + bv, 0.f));
    }
}

// ------- layer 3 + classifier fused: no H3 global round-trip ---------------
__global__ __launch_bounds__(256) void k_gather_gemm_cls(
    const int* __restrict__ row_start, const int* __restrict__ row_end,
    const int* __restrict__ srcs,
    const unsigned short* __restrict__ Hin, const unsigned* __restrict__ pWl,
    const float* __restrict__ bl, const unsigned* __restrict__ pWc,
    const float* __restrict__ bc, float* __restrict__ out)
{
    __shared__ unsigned sup[16][36];
    __shared__ unsigned short sh2[16][72];   // relu'd H3 tile, bf16
    __shared__ int ssrc[SSEG];
    const int t = threadIdx.x;
    const int row0 = blockIdx.x * 16;
    gather_tile(row_start, row_end, srcs, Hin, sup, ssrc, row0, t);
    __syncthreads();

    const int lane = t & 63;
    const int w    = t >> 6;
    const int quad = lane >> 4;
    const int m    = lane & 15;
    const bf16x8* pb = (const bf16x8*)pWl;
    f32x4 acc = {0.f, 0.f, 0.f, 0.f};
    #pragma unroll
    for (int ks = 0; ks < 2; ++ks) {
        const bf16x8 a  = *(const bf16x8*)&sup[m][ks * 16 + quad * 4];
        const bf16x8 bb = pb[((w << 1) + ks) * 64 + lane];
        acc = __builtin_amdgcn_mfma_f32_16x16x32_bf16(a, bb, acc, 0, 0, 0);
    }
    const int jc = w * 16 + m;
    const float bv = bl[jc];
    #pragma unroll
    for (int r = 0; r < 4; ++r)
        sh2[quad * 4 + r][jc] = f2bf(fmaxf(acc[r] + bv, 0.f));
    __syncthreads();

    // classifier: waves 0-2 each compute 16 output cols (48 padded >= NCLS)
    if (w < 3) {
        const bf16x8* pbc = (const bf16x8*)pWc;
        f32x4 c = {0.f, 0.f, 0.f, 0.f};
        #pragma unroll
        for (int ks = 0; ks < 2; ++ks) {
            const bf16x8 a = *(const bf16x8*)&sh2[m][ks * 32 + quad * 8];
            c = __builtin_amdgcn_mfma_f32_16x16x32_bf16(a, pbc[(w * 2 + ks) * 64 + lane], c, 0, 0, 0);
        }
        const int col = w * 16 + m;
        if (col < NCLS) {
            const float bcv = bc[col];
            #pragma unroll
            for (int r = 0; r < 4; ++r)
                out[(size_t)(row0 + quad * 4 + r) * NCLS + col] = c[r] + bcv;
        }
    }
}

extern "C" void kernel_launch(void* const* d_in, const int* in_sizes, int n_in,
                              void* d_out, int out_size, void* d_ws, size_t ws_size,
                              hipStream_t stream)
{
    const float* x        = (const float*)d_in[0];
    const int*   ei       = (const int*)  d_in[1];
    const float* W_in     = (const float*)d_in[2];
    const float* b_in     = (const float*)d_in[3];
    const float* W_layers = (const float*)d_in[4];
    const float* b_layers = (const float*)d_in[5];
    const float* W_cls    = (const float*)d_in[6];
    const float* b_cls    = (const float*)d_in[7];
    float* out = (float*)d_out;

    // ws layout (~45.3 MB): H0, H1, build scratch, prepped weight fragments
    unsigned short* H0 = (unsigned short*)d_ws;
    unsigned short* H1 = H0 + (size_t)(N_NODES + 1) * HID;
    int* wsp       = (int*)(H1 + (size_t)(N_NODES + 1) * HID);
    int* pairs     = wsp;                         // NBUCK*BCAP = 2.40M ints
    int* srcs      = wsp + NBUCK * BCAP;          // 2.40M ints
    int* row_start = wsp + 2 * NBUCK * BCAP;      // 100000 (pad 100096)
    int* row_end   = row_start + 100096;          // 100000
    int* cursor    = row_end + 100096;            // 782 (pad 1024)
    unsigned* pWin = (unsigned*)(cursor + 1024);  // 4096
    unsigned* pWl  = pWin + 4096;                 // 6144 (3 layers x 2048)
    unsigned* pWc  = pWl + 6144;                  // 1536

    hipMemsetAsync(cursor, 0, 1024 * sizeof(int), stream);

    k_part_prep<<<NTILE + PREP_BLKS, 256, 0, stream>>>(
        ei, cursor, pairs, W_in, W_layers, W_cls, pWin, pWl, pWc, H0, H1);

    k_bsort_ingemm<<<NBUCK + IN_BLOCKS, 256, 0, stream>>>(
        cursor, pairs, srcs, row_start, row_end, x, pWin, b_in, H0);

    const int gemm_blocks = N_NODES / 16;         // 6250 (gather)
    k_gather_gemm<<<gemm_blocks, 256, 0, stream>>>(
        row_start, row_end, srcs, H0, pWl,          b_layers,        H1);
    k_gather_gemm<<<gemm_blocks, 256, 0, stream>>>(
        row_start, row_end, srcs, H1, pWl + 2048,   b_layers + HID,  H0);
    k_gather_gemm_cls<<<gemm_blocks, 256, 0, stream>>>(
        row_start, row_end, srcs, H0, pWl + 4096,   b_layers + 2*HID,
        pWc, b_cls, out);
}

// Round 6
// 224.069 us; speedup vs baseline: 1.0606x; 1.0606x over previous
//
#include <hip/hip_runtime.h>
#include <hip/hip_bf16.h>

#define N_NODES 100000
#define E_NUM   1600000
#define IN_DIM  128
#define HID     64
#define NCLS    40
#define NBUCK   782      // ceil(N_NODES/128); bucket b owns nodes [b*128, b*128+128)
#define TILE_E  8192     // big tiles: bucket runs of ~10 slots -> write locality
#define NTILE   196      // ceil(E_NUM / TILE_E)
#define BCAP    3072     // per-bucket capacity incl. pad-to-8
#define ZROW    N_NODES  // sentinel node whose H row is all zeros
#define NTILES_M 6250    // N_NODES / 16
#define IN_BLOCKS 1563   // ceil(NTILES_M / 4)
#define PREP_BLKS 23     // ceil(11776 / 512)

typedef __attribute__((ext_vector_type(8))) short bf16x8;
typedef __attribute__((ext_vector_type(4))) float f32x4;

// bf16 helpers
static __device__ __forceinline__ float bflo(unsigned u) {
    return __uint_as_float(u << 16);
}
static __device__ __forceinline__ float bfhi(unsigned u) {
    return __uint_as_float(u & 0xFFFF0000u);
}
static __device__ __forceinline__ unsigned short f2bf(float f) {
    unsigned u = __float_as_uint(f);
    u += 0x7FFFu + ((u >> 16) & 1u);     // round-to-nearest-even
    return (unsigned short)(u >> 16);
}
static __device__ __forceinline__ unsigned pack2bf(float lo, float hi) {
    return (unsigned)f2bf(lo) | ((unsigned)f2bf(hi) << 16);
}

// ---- K1 (512 threads): blocks 0..195 partition edges (8 waves/CU halves
//      the exposed {load->LDS-atomic} latency chain vs 256-thread blocks);
//      blocks 196..218 pre-swizzle weights + zero H sentinel rows.
__global__ __launch_bounds__(512) void k_part_prep(
    const int* __restrict__ ei, int* __restrict__ cursor, int* __restrict__ pairs,
    const float* __restrict__ Win, const float* __restrict__ Wl,
    const float* __restrict__ Wc, unsigned* __restrict__ pWin,
    unsigned* __restrict__ pWl, unsigned* __restrict__ pWc,
    unsigned short* __restrict__ H0, unsigned short* __restrict__ H1)
{
    __shared__ int lh[NBUCK];
    __shared__ int lbase[NBUCK];
    __shared__ int lcnt[NBUCK];
    const int t = threadIdx.x;

    if (blockIdx.x < NTILE) {
        for (int i = t; i < NBUCK; i += 512) { lh[i] = 0; lcnt[i] = 0; }
        __syncthreads();
        const int e0 = blockIdx.x * TILE_E;
        // pass 1: histogram — batch 8 loads ahead of the LDS atomics
        #pragma unroll
        for (int k = 0; k < TILE_E; k += 4096) {
            int d[8];
            #pragma unroll
            for (int j = 0; j < 8; ++j) {
                const int e = e0 + k + j * 512 + t;
                d[j] = (e < E_NUM) ? ei[E_NUM + e] : -1;
            }
            #pragma unroll
            for (int j = 0; j < 8; ++j)
                if (d[j] >= 0) atomicAdd(&lh[d[j] >> 7], 1);
        }
        __syncthreads();
        for (int i = t; i < NBUCK; i += 512)
            lbase[i] = lh[i] ? atomicAdd(&cursor[i], lh[i]) : 0;
        __syncthreads();
        // pass 2: scatter — batch 4 edges (8 loads) ahead of atomic+store
        #pragma unroll
        for (int k = 0; k < TILE_E; k += 2048) {
            int s[4], d[4];
            #pragma unroll
            for (int j = 0; j < 4; ++j) {
                const int e = e0 + k + j * 512 + t;
                if (e < E_NUM) { s[j] = ei[e]; d[j] = ei[E_NUM + e]; }
                else           { s[j] = -1;    d[j] = -1; }
            }
            #pragma unroll
            for (int j = 0; j < 4; ++j) {
                if (d[j] >= 0) {
                    const int bkt = d[j] >> 7;
                    const int r   = lbase[bkt] + atomicAdd(&lcnt[bkt], 1);
                    if (r < BCAP) pairs[bkt * BCAP + r] = (s[j] << 7) | (d[j] & 127);
                }
            }
        }
        return;
    }

    // ---- prep half ----
    const int bi = blockIdx.x - NTILE;
    if (bi == 0 && t < 32) {
        ((unsigned*)(H0 + (size_t)ZROW * HID))[t] = 0;
        ((unsigned*)(H1 + (size_t)ZROW * HID))[t] = 0;
    }
    int i = bi * 512 + t;
    if (i < 4096) {                       // W_in: 4 ntiles x 4 ksteps
        const int nt = i >> 10, ks = (i >> 8) & 3, ln = (i >> 2) & 63, jp = i & 3;
        const int n = nt * 16 + (ln & 15);
        const int k = ks * 32 + (ln >> 4) * 8 + jp * 2;
        pWin[i] = pack2bf(Win[k * HID + n], Win[(k + 1) * HID + n]);
    } else if (i < 10240) {               // 3 layers: 4 ntiles x 2 ksteps each
        int j = i - 4096;
        const int l = j >> 11; j &= 2047;
        const int nt = j >> 9, ks = (j >> 8) & 1, ln = (j >> 2) & 63, jp = j & 3;
        const int n = nt * 16 + (ln & 15);
        const int k = ks * 32 + (ln >> 4) * 8 + jp * 2;
        const float* w = Wl + (size_t)l * HID * HID;
        pWl[i - 4096] = pack2bf(w[k * HID + n], w[(k + 1) * HID + n]);
    } else if (i < 11776) {               // W_cls: 3 ntiles (48 cols, pad) x 2 ks
        const int j = i - 10240;
        const int nt = j >> 9, ks = (j >> 8) & 1, ln = (j >> 2) & 63, jp = j & 3;
        const int n = nt * 16 + (ln & 15);
        const int k = ks * 32 + (ln >> 4) * 8 + jp * 2;
        pWc[j] = (n < NCLS) ? pack2bf(Wc[k * NCLS + n], Wc[(k + 1) * NCLS + n]) : 0u;
    }
}

// ---- K2: blocks 0..781 bsort (per-bucket counting sort -> padded CSR);
//          blocks 782+ input GEMM. They co-run (m114: time = max).
__global__ __launch_bounds__(256) void k_bsort_ingemm(
    const int* __restrict__ cursor, const int* __restrict__ pairs,
    int* __restrict__ srcs, int* __restrict__ row_start, int* __restrict__ row_end,
    const float* __restrict__ x, const unsigned* __restrict__ pWin,
    const float* __restrict__ b, unsigned short* __restrict__ H0)
{
    __shared__ int cnt[128];
    __shared__ int sc[128];
    __shared__ int cur[128];
    const int t = threadIdx.x;

    if (blockIdx.x < NBUCK) {
        const int bk = blockIdx.x;
        const int beg = bk * BCAP;
        const int n_e = min(cursor[bk], BCAP);
        if (t < 128) cnt[t] = 0;
        __syncthreads();
        // count — batch 4 loads ahead of atomics
        for (int i = t; i < n_e; i += 1024) {
            const int p0 = pairs[beg + i];
            const int p1 = (i + 256 < n_e) ? pairs[beg + i + 256] : -1;
            const int p2 = (i + 512 < n_e) ? pairs[beg + i + 512] : -1;
            const int p3 = (i + 768 < n_e) ? pairs[beg + i + 768] : -1;
            atomicAdd(&cnt[p0 & 127], 1);
            if (p1 >= 0) atomicAdd(&cnt[p1 & 127], 1);
            if (p2 >= 0) atomicAdd(&cnt[p2 & 127], 1);
            if (p3 >= 0) atomicAdd(&cnt[p3 & 127], 1);
        }
        __syncthreads();
        if (t < 128) sc[t] = (cnt[t] + 7) & ~7;
        __syncthreads();
        for (int off = 1; off < 128; off <<= 1) {
            int a = (t < 128 && t >= off) ? sc[t - off] : 0;
            __syncthreads();
            if (t < 128) sc[t] += a;
            __syncthreads();
        }
        const int node0 = bk << 7;
        if (t < 128) {
            const int pc = (cnt[t] + 7) & ~7;
            const int ex = sc[t] - pc;
            cur[t] = ex;
            const int node = node0 + t;
            if (node < N_NODES) {
                const int rs = beg + ex;
                row_start[node] = rs;
                row_end  [node] = min(rs + pc, beg + BCAP);
            }
            const int fb = beg + ex + cnt[t];
            const int fe = min(beg + ex + pc, beg + BCAP);
            for (int i = fb; i < fe; ++i) srcs[i] = ZROW;
        }
        __syncthreads();
        // scatter — batch 4 loads
        for (int i = t; i < n_e; i += 1024) {
            const int p0 = pairs[beg + i];
            const int p1 = (i + 256 < n_e) ? pairs[beg + i + 256] : -1;
            const int p2 = (i + 512 < n_e) ? pairs[beg + i + 512] : -1;
            const int p3 = (i + 768 < n_e) ? pairs[beg + i + 768] : -1;
            { const int r = atomicAdd(&cur[p0 & 127], 1); if (r < BCAP) srcs[beg + r] = p0 >> 7; }
            if (p1 >= 0) { const int r = atomicAdd(&cur[p1 & 127], 1); if (r < BCAP) srcs[beg + r] = p1 >> 7; }
            if (p2 >= 0) { const int r = atomicAdd(&cur[p2 & 127], 1); if (r < BCAP) srcs[beg + r] = p2 >> 7; }
            if (p3 >= 0) { const int r = atomicAdd(&cur[p3 & 127], 1); if (r < BCAP) srcs[beg + r] = p3 >> 7; }
        }
        return;
    }

    // ---------------- in_gemm block (MFMA, register-direct) ----------------
    const int blk  = blockIdx.x - NBUCK;
    const int lane = t & 63;
    const int w    = t >> 6;
    const int tile = blk * 4 + w;
    if (tile >= NTILES_M) return;
    const int quad = lane >> 4;
    const int mrow = lane & 15;
    const int gr   = tile * 16 + mrow;            // < 100000 always (N%16==0)
    const float* xr = x + (size_t)gr * IN_DIM;
    const bf16x8* pb = (const bf16x8*)pWin;

    f32x4 acc0 = {0.f, 0.f, 0.f, 0.f};
    f32x4 acc1 = {0.f, 0.f, 0.f, 0.f};
    f32x4 acc2 = {0.f, 0.f, 0.f, 0.f};
    f32x4 acc3 = {0.f, 0.f, 0.f, 0.f};
    #pragma unroll
    for (int ks = 0; ks < 4; ++ks) {
        const float4 v0 = *(const float4*)(xr + ks * 32 + quad * 8);
        const float4 v1 = *(const float4*)(xr + ks * 32 + quad * 8 + 4);
        union { unsigned u[4]; bf16x8 v; } au;
        au.u[0] = pack2bf(v0.x, v0.y);
        au.u[1] = pack2bf(v0.z, v0.w);
        au.u[2] = pack2bf(v1.x, v1.y);
        au.u[3] = pack2bf(v1.z, v1.w);
        acc0 = __builtin_amdgcn_mfma_f32_16x16x32_bf16(au.v, pb[       ks * 64 + lane], acc0, 0, 0, 0);
        acc1 = __builtin_amdgcn_mfma_f32_16x16x32_bf16(au.v, pb[256 +  ks * 64 + lane], acc1, 0, 0, 0);
        acc2 = __builtin_amdgcn_mfma_f32_16x16x32_bf16(au.v, pb[512 +  ks * 64 + lane], acc2, 0, 0, 0);
        acc3 = __builtin_amdgcn_mfma_f32_16x16x32_bf16(au.v, pb[768 +  ks * 64 + lane], acc3, 0, 0, 0);
    }

    const int colg = lane & 15;
    const int nodeb = tile * 16 + quad * 4;
    const float bv0 = b[     colg];
    const float bv1 = b[16 + colg];
    const float bv2 = b[32 + colg];
    const float bv3 = b[48 + colg];
    #pragma unroll
    for (int r = 0; r < 4; ++r) {
        const size_t ob = (size_t)(nodeb + r) * HID;
        H0[ob      + colg] = f2bf(fmaxf(acc0[r] + bv0, 0.f));
        H0[ob + 16 + colg] = f2bf(fmaxf(acc1[r] + bv1, 0.f));
        H0[ob + 32 + colg] = f2bf(fmaxf(acc2[r] + bv2, 0.f));
        H0[ob + 48 + colg] = f2bf(fmaxf(acc3[r] + bv3, 0.f));
    }
}

// ---- shared gather phase: fills sup[16][36] with packed-bf16 U rows -------
// 16 lanes per node (2 edge-parity subgroups x 8 chunk lanes x dwordx4).
// srcs indices are software-pipelined: next iteration's 8 indices are
// fetched right after the current H loads issue, riding under their
// latency. Tail (rem&8) consumes the prefetched batch — bit-identical.
#define ACC8(u) do { \
        a0 += bflo((u).x); a1 += bfhi((u).x); \
        a2 += bflo((u).y); a3 += bfhi((u).y); \
        a4 += bflo((u).z); a5 += bfhi((u).z); \
        a6 += bflo((u).w); a7 += bfhi((u).w); } while (0)

#define LOADH(s) (*(const uint4*)(Hin + (size_t)(s) * HID + 8 * fl))

static __device__ __forceinline__ void gather_tile(
    const int* __restrict__ row_start, const int* __restrict__ row_end,
    const int* __restrict__ srcs, const unsigned short* __restrict__ Hin,
    unsigned (*sup)[36], int row0, int t)
{
    const int lane = t & 63;
    const int w    = t >> 6;
    const int nd   = lane >> 4;          // node within wave's group of 4
    const int sub  = (lane >> 3) & 1;    // edge-parity subgroup
    const int fl   = lane & 7;           // 16B chunk within 128B row
    const int node = row0 + (w << 2) + nd;

    const int rs = row_start[node];
    int rem = row_end[node] - rs;        // multiple of 8 (padded with ZROW)
    if (rem < 0) rem = 0;                // bucket-overflow clamp can go negative
    int i = rs + sub;
    const int imax = NBUCK * BCAP - 16;  // safe prefetch base (clamped)

    // self row: independent load, issue before the gather loop
    const uint4 us = LOADH(node);

    // initial index batch (unguarded, address-clamped; values used only
    // when rem >= 8, in which case they are genuine row slots)
    int s0, s1, s2, s3, s4, s5, s6, s7;
    {
        const int ip = min(i, imax);
        s0 = srcs[ip     ]; s1 = srcs[ip +  2];
        s2 = srcs[ip +  4]; s3 = srcs[ip +  6];
        s4 = srcs[ip +  8]; s5 = srcs[ip + 10];
        s6 = srcs[ip + 12]; s7 = srcs[ip + 14];
    }

    float a0 = 0.f, a1 = 0.f, a2 = 0.f, a3 = 0.f;
    float a4 = 0.f, a5 = 0.f, a6 = 0.f, a7 = 0.f;

    for (int nfull = rem >> 4; nfull > 0; --nfull) {
        const uint4 u0 = LOADH(s0); const uint4 u1 = LOADH(s1);
        const uint4 u2 = LOADH(s2); const uint4 u3 = LOADH(s3);
        const uint4 u4 = LOADH(s4); const uint4 u5 = LOADH(s5);
        const uint4 u6 = LOADH(s6); const uint4 u7 = LOADH(s7);
        i += 16;
        const int ip = min(i, imax);     // next-iter (or tail) indices
        const int n0 = srcs[ip     ], n1 = srcs[ip +  2];
        const int n2 = srcs[ip +  4], n3 = srcs[ip +  6];
        const int n4 = srcs[ip +  8], n5 = srcs[ip + 10];
        const int n6 = srcs[ip + 12], n7 = srcs[ip + 14];
        ACC8(u0); ACC8(u1); ACC8(u2); ACC8(u3);
        ACC8(u4); ACC8(u5); ACC8(u6); ACC8(u7);
        s0 = n0; s1 = n1; s2 = n2; s3 = n3;
        s4 = n4; s5 = n5; s6 = n6; s7 = n7;
    }
    if (rem & 8) {
        const uint4 u0 = LOADH(s0); const uint4 u1 = LOADH(s1);
        const uint4 u2 = LOADH(s2); const uint4 u3 = LOADH(s3);
        ACC8(u0); ACC8(u1); ACC8(u2); ACC8(u3);
    }

    // reduce across the two edge-parity subgroups (xor lane bit 3)
    a0 += __shfl_xor(a0, 8, 64); a1 += __shfl_xor(a1, 8, 64);
    a2 += __shfl_xor(a2, 8, 64); a3 += __shfl_xor(a3, 8, 64);
    a4 += __shfl_xor(a4, 8, 64); a5 += __shfl_xor(a5, 8, 64);
    a6 += __shfl_xor(a6, 8, 64); a7 += __shfl_xor(a7, 8, 64);

    // add self row (h + agg)
    ACC8(us);

    const int r = (w << 2) + nd;
    if (sub == 0) {
        sup[r][4 * fl    ] = pack2bf(a0, a1);
        sup[r][4 * fl + 1] = pack2bf(a2, a3);
    } else {
        sup[r][4 * fl + 2] = pack2bf(a4, a5);
        sup[r][4 * fl + 3] = pack2bf(a6, a7);
    }
}

// ------- layers 1-2: gather + MFMA layer GEMM, write bf16 Hout -------------
__global__ __launch_bounds__(256) void k_gather_gemm(
    const int* __restrict__ row_start, const int* __restrict__ row_end,
    const int* __restrict__ srcs,
    const unsigned short* __restrict__ Hin, const unsigned* __restrict__ pWl,
    const float* __restrict__ bl, unsigned short* __restrict__ Hout)
{
    __shared__ unsigned sup[16][36];
    const int t = threadIdx.x;
    const int row0 = blockIdx.x * 16;
    gather_tile(row_start, row_end, srcs, Hin, sup, row0, t);
    __syncthreads();

    const int lane = t & 63;
    const int w    = t >> 6;
    const int quad = lane >> 4;
    const int m    = lane & 15;
    const bf16x8* pb = (const bf16x8*)pWl;
    f32x4 acc = {0.f, 0.f, 0.f, 0.f};
    #pragma unroll
    for (int ks = 0; ks < 2; ++ks) {
        const bf16x8 a  = *(const bf16x8*)&sup[m][ks * 16 + quad * 4];
        const bf16x8 bb = pb[((w << 1) + ks) * 64 + lane];
        acc = __builtin_amdgcn_mfma_f32_16x16x32_bf16(a, bb, acc, 0, 0, 0);
    }
    const int jc = w * 16 + m;
    const float bv = bl[jc];
    #pragma unroll
    for (int r = 0; r < 4; ++r) {
        const int node = row0 + quad * 4 + r;
        Hout[(size_t)node * HID + jc] = f2bf(fmaxf(acc[r] + bv, 0.f));
    }
}

// ------- layer 3 + classifier fused: no H3 global round-trip ---------------
__global__ __launch_bounds__(256) void k_gather_gemm_cls(
    const int* __restrict__ row_start, const int* __restrict__ row_end,
    const int* __restrict__ srcs,
    const unsigned short* __restrict__ Hin, const unsigned* __restrict__ pWl,
    const float* __restrict__ bl, const unsigned* __restrict__ pWc,
    const float* __restrict__ bc, float* __restrict__ out)
{
    __shared__ unsigned sup[16][36];
    __shared__ unsigned short sh2[16][72];   // relu'd H3 tile, bf16
    const int t = threadIdx.x;
    const int row0 = blockIdx.x * 16;
    gather_tile(row_start, row_end, srcs, Hin, sup, row0, t);
    __syncthreads();

    const int lane = t & 63;
    const int w    = t >> 6;
    const int quad = lane >> 4;
    const int m    = lane & 15;
    const bf16x8* pb = (const bf16x8*)pWl;
    f32x4 acc = {0.f, 0.f, 0.f, 0.f};
    #pragma unroll
    for (int ks = 0; ks < 2; ++ks) {
        const bf16x8 a  = *(const bf16x8*)&sup[m][ks * 16 + quad * 4];
        const bf16x8 bb = pb[((w << 1) + ks) * 64 + lane];
        acc = __builtin_amdgcn_mfma_f32_16x16x32_bf16(a, bb, acc, 0, 0, 0);
    }
    const int jc = w * 16 + m;
    const float bv = bl[jc];
    #pragma unroll
    for (int r = 0; r < 4; ++r)
        sh2[quad * 4 + r][jc] = f2bf(fmaxf(acc[r] + bv, 0.f));
    __syncthreads();

    // classifier: waves 0-2 each compute 16 output cols (48 padded >= NCLS)
    if (w < 3) {
        const bf16x8* pbc = (const bf16x8*)pWc;
        f32x4 c = {0.f, 0.f, 0.f, 0.f};
        #pragma unroll
        for (int ks = 0; ks < 2; ++ks) {
            const bf16x8 a = *(const bf16x8*)&sh2[m][ks * 32 + quad * 8];
            c = __builtin_amdgcn_mfma_f32_16x16x32_bf16(a, pbc[(w * 2 + ks) * 64 + lane], c, 0, 0, 0);
        }
        const int col = w * 16 + m;
        if (col < NCLS) {
            const float bcv = bc[col];
            #pragma unroll
            for (int r = 0; r < 4; ++r)
                out[(size_t)(row0 + quad * 4 + r) * NCLS + col] = c[r] + bcv;
        }
    }
}

extern "C" void kernel_launch(void* const* d_in, const int* in_sizes, int n_in,
                              void* d_out, int out_size, void* d_ws, size_t ws_size,
                              hipStream_t stream)
{
    const float* x        = (const float*)d_in[0];
    const int*   ei       = (const int*)  d_in[1];
    const float* W_in     = (const float*)d_in[2];
    const float* b_in     = (const float*)d_in[3];
    const float* W_layers = (const float*)d_in[4];
    const float* b_layers = (const float*)d_in[5];
    const float* W_cls    = (const float*)d_in[6];
    const float* b_cls    = (const float*)d_in[7];
    float* out = (float*)d_out;

    // ws layout (~45.3 MB): H0, H1, build scratch, prepped weight fragments
    unsigned short* H0 = (unsigned short*)d_ws;
    unsigned short* H1 = H0 + (size_t)(N_NODES + 1) * HID;
    int* wsp       = (int*)(H1 + (size_t)(N_NODES + 1) * HID);
    int* pairs     = wsp;                         // NBUCK*BCAP = 2.40M ints
    int* srcs      = wsp + NBUCK * BCAP;          // 2.40M ints
    int* row_start = wsp + 2 * NBUCK * BCAP;      // 100000 (pad 100096)
    int* row_end   = row_start + 100096;          // 100000
    int* cursor    = row_end + 100096;            // 782 (pad 1024)
    unsigned* pWin = (unsigned*)(cursor + 1024);  // 4096
    unsigned* pWl  = pWin + 4096;                 // 6144 (3 layers x 2048)
    unsigned* pWc  = pWl + 6144;                  // 1536

    hipMemsetAsync(cursor, 0, 1024 * sizeof(int), stream);

    k_part_prep<<<NTILE + PREP_BLKS, 512, 0, stream>>>(
        ei, cursor, pairs, W_in, W_layers, W_cls, pWin, pWl, pWc, H0, H1);

    k_bsort_ingemm<<<NBUCK + IN_BLOCKS, 256, 0, stream>>>(
        cursor, pairs, srcs, row_start, row_end, x, pWin, b_in, H0);

    const int gemm_blocks = N_NODES / 16;         // 6250 (gather)
    k_gather_gemm<<<gemm_blocks, 256, 0, stream>>>(
        row_start, row_end, srcs, H0, pWl,          b_layers,        H1);
    k_gather_gemm<<<gemm_blocks, 256, 0, stream>>>(
        row_start, row_end, srcs, H1, pWl + 2048,   b_layers + HID,  H0);
    k_gather_gemm_cls<<<gemm_blocks, 256, 0, stream>>>(
        row_start, row_end, srcs, H0, pWl + 4096,   b_layers + 2*HID,
        pWc, b_cls, out);
}

// Round 7
// 207.943 us; speedup vs baseline: 1.1429x; 1.0775x over previous
//
#include <hip/hip_runtime.h>
#include <hip/hip_bf16.h>

#define N_NODES 100000
#define E_NUM   1600000
#define IN_DIM  128
#define HID     64       // also = H row size in BYTES now (1 B fp8/elem)
#define NCLS    40
#define NBUCK   782      // ceil(N_NODES/128); bucket b owns nodes [b*128, b*128+128)
#define TILE_E  8192     // big tiles: bucket runs of ~10 slots -> write locality
#define NTILE   196      // ceil(E_NUM / TILE_E)
#define BCAP    3072     // per-bucket capacity incl. pad-to-8
#define ZROW    N_NODES  // sentinel node whose H row is all zeros
#define NTILES_M 6250    // N_NODES / 16
#define IN_BLOCKS 1563   // ceil(NTILES_M / 4)
#define PREP_BLKS 23     // ceil(11776 / 512)

typedef __attribute__((ext_vector_type(8))) short bf16x8;
typedef __attribute__((ext_vector_type(4))) float f32x4;
typedef __attribute__((ext_vector_type(2))) float f32x2;

// bf16 helpers
static __device__ __forceinline__ unsigned short f2bf(float f) {
    unsigned u = __float_as_uint(f);
    u += 0x7FFFu + ((u >> 16) & 1u);     // round-to-nearest-even
    return (unsigned short)(u >> 16);
}
static __device__ __forceinline__ unsigned pack2bf(float lo, float hi) {
    return (unsigned)f2bf(lo) | ((unsigned)f2bf(hi) << 16);
}

// ---- fp8 e4m3 (OCP) helpers: H is stored in fp8 to halve the random
//      gather traffic (128B -> 64B per row). MFMA math stays f32/bf16.
static __device__ __forceinline__ float fp8_1(unsigned b) {
    const unsigned e = (b >> 3) & 15u, m = b & 7u, s = b >> 7;
    float v = e ? __uint_as_float(((e + 120u) << 23) | (m << 20))
                : (float)m * 0.001953125f;           // denorm: m * 2^-9
    return s ? -v : v;
}
static __device__ __forceinline__ void dec4(unsigned w, float& x0, float& x1,
                                            float& x2, float& x3) {
#if __has_builtin(__builtin_amdgcn_cvt_pk_f32_fp8)
    f32x2 lo = __builtin_amdgcn_cvt_pk_f32_fp8((int)w, false);
    f32x2 hi = __builtin_amdgcn_cvt_pk_f32_fp8((int)w, true);
    x0 = lo[0]; x1 = lo[1]; x2 = hi[0]; x3 = hi[1];
#else
    x0 = fp8_1(w & 0xFFu);         x1 = fp8_1((w >> 8) & 0xFFu);
    x2 = fp8_1((w >> 16) & 0xFFu); x3 = fp8_1(w >> 24);
#endif
}
static __device__ __forceinline__ unsigned char f2fp8(float f) {
#if __has_builtin(__builtin_amdgcn_cvt_pk_fp8_f32)
    return (unsigned char)(__builtin_amdgcn_cvt_pk_fp8_f32(f, 0.f, 0, false) & 0xFF);
#else
    if (!(f > 0.f)) return 0;                 // inputs are post-relu (>= 0)
    if (f >= 448.f) return 0x7E;              // max finite e4m3fn
    unsigned u = __float_as_uint(f);
    u += 0x7FFFFu + ((u >> 20) & 1u);         // RNE drop 20 mantissa bits
    const int e = (int)(u >> 23) - 120;
    if (e <= 0) {                             // denormal
        int q = (int)(f * 512.f + 0.5f);
        return (unsigned char)(q > 7 ? 8 : q);
    }
    unsigned r = ((unsigned)e << 3) | ((u >> 20) & 7u);
    return (unsigned char)(r > 0x7Eu ? 0x7Eu : r);
#endif
}

// ---- K1 (512 threads): blocks 0..195 partition edges; blocks 196..218
//      pre-swizzle weights + zero H sentinel rows (now 64 B each).
__global__ __launch_bounds__(512) void k_part_prep(
    const int* __restrict__ ei, int* __restrict__ cursor, int* __restrict__ pairs,
    const float* __restrict__ Win, const float* __restrict__ Wl,
    const float* __restrict__ Wc, unsigned* __restrict__ pWin,
    unsigned* __restrict__ pWl, unsigned* __restrict__ pWc,
    unsigned char* __restrict__ H0, unsigned char* __restrict__ H1)
{
    __shared__ int lh[NBUCK];
    __shared__ int lbase[NBUCK];
    __shared__ int lcnt[NBUCK];
    const int t = threadIdx.x;

    if (blockIdx.x < NTILE) {
        for (int i = t; i < NBUCK; i += 512) { lh[i] = 0; lcnt[i] = 0; }
        __syncthreads();
        const int e0 = blockIdx.x * TILE_E;
        // pass 1: histogram — batch 8 loads ahead of the LDS atomics
        #pragma unroll
        for (int k = 0; k < TILE_E; k += 4096) {
            int d[8];
            #pragma unroll
            for (int j = 0; j < 8; ++j) {
                const int e = e0 + k + j * 512 + t;
                d[j] = (e < E_NUM) ? ei[E_NUM + e] : -1;
            }
            #pragma unroll
            for (int j = 0; j < 8; ++j)
                if (d[j] >= 0) atomicAdd(&lh[d[j] >> 7], 1);
        }
        __syncthreads();
        for (int i = t; i < NBUCK; i += 512)
            lbase[i] = lh[i] ? atomicAdd(&cursor[i], lh[i]) : 0;
        __syncthreads();
        // pass 2: scatter — batch 4 edges (8 loads) ahead of atomic+store
        #pragma unroll
        for (int k = 0; k < TILE_E; k += 2048) {
            int s[4], d[4];
            #pragma unroll
            for (int j = 0; j < 4; ++j) {
                const int e = e0 + k + j * 512 + t;
                if (e < E_NUM) { s[j] = ei[e]; d[j] = ei[E_NUM + e]; }
                else           { s[j] = -1;    d[j] = -1; }
            }
            #pragma unroll
            for (int j = 0; j < 4; ++j) {
                if (d[j] >= 0) {
                    const int bkt = d[j] >> 7;
                    const int r   = lbase[bkt] + atomicAdd(&lcnt[bkt], 1);
                    if (r < BCAP) pairs[bkt * BCAP + r] = (s[j] << 7) | (d[j] & 127);
                }
            }
        }
        return;
    }

    // ---- prep half ----
    const int bi = blockIdx.x - NTILE;
    if (bi == 0 && t < 32) {
        if (t < 16) ((unsigned*)(H0 + (size_t)ZROW * HID))[t] = 0;
        else        ((unsigned*)(H1 + (size_t)ZROW * HID))[t - 16] = 0;
    }
    int i = bi * 512 + t;
    if (i < 4096) {                       // W_in: 4 ntiles x 4 ksteps
        const int nt = i >> 10, ks = (i >> 8) & 3, ln = (i >> 2) & 63, jp = i & 3;
        const int n = nt * 16 + (ln & 15);
        const int k = ks * 32 + (ln >> 4) * 8 + jp * 2;
        pWin[i] = pack2bf(Win[k * HID + n], Win[(k + 1) * HID + n]);
    } else if (i < 10240) {               // 3 layers: 4 ntiles x 2 ksteps each
        int j = i - 4096;
        const int l = j >> 11; j &= 2047;
        const int nt = j >> 9, ks = (j >> 8) & 1, ln = (j >> 2) & 63, jp = j & 3;
        const int n = nt * 16 + (ln & 15);
        const int k = ks * 32 + (ln >> 4) * 8 + jp * 2;
        const float* w = Wl + (size_t)l * HID * HID;
        pWl[i - 4096] = pack2bf(w[k * HID + n], w[(k + 1) * HID + n]);
    } else if (i < 11776) {               // W_cls: 3 ntiles (48 cols, pad) x 2 ks
        const int j = i - 10240;
        const int nt = j >> 9, ks = (j >> 8) & 1, ln = (j >> 2) & 63, jp = j & 3;
        const int n = nt * 16 + (ln & 15);
        const int k = ks * 32 + (ln >> 4) * 8 + jp * 2;
        pWc[j] = (n < NCLS) ? pack2bf(Wc[k * NCLS + n], Wc[(k + 1) * NCLS + n]) : 0u;
    }
}

// ---- K2: blocks 0..781 bsort (per-bucket counting sort -> padded CSR);
//          blocks 782+ input GEMM (writes H0 in fp8). Co-run (time = max).
__global__ __launch_bounds__(256) void k_bsort_ingemm(
    const int* __restrict__ cursor, const int* __restrict__ pairs,
    int* __restrict__ srcs, int* __restrict__ row_start, int* __restrict__ row_end,
    const float* __restrict__ x, const unsigned* __restrict__ pWin,
    const float* __restrict__ b, unsigned char* __restrict__ H0)
{
    __shared__ int cnt[128];
    __shared__ int sc[128];
    __shared__ int cur[128];
    const int t = threadIdx.x;

    if (blockIdx.x < NBUCK) {
        const int bk = blockIdx.x;
        const int beg = bk * BCAP;
        const int n_e = min(cursor[bk], BCAP);
        if (t < 128) cnt[t] = 0;
        __syncthreads();
        // count — batch 4 loads ahead of atomics
        for (int i = t; i < n_e; i += 1024) {
            const int p0 = pairs[beg + i];
            const int p1 = (i + 256 < n_e) ? pairs[beg + i + 256] : -1;
            const int p2 = (i + 512 < n_e) ? pairs[beg + i + 512] : -1;
            const int p3 = (i + 768 < n_e) ? pairs[beg + i + 768] : -1;
            atomicAdd(&cnt[p0 & 127], 1);
            if (p1 >= 0) atomicAdd(&cnt[p1 & 127], 1);
            if (p2 >= 0) atomicAdd(&cnt[p2 & 127], 1);
            if (p3 >= 0) atomicAdd(&cnt[p3 & 127], 1);
        }
        __syncthreads();
        if (t < 128) sc[t] = (cnt[t] + 7) & ~7;
        __syncthreads();
        for (int off = 1; off < 128; off <<= 1) {
            int a = (t < 128 && t >= off) ? sc[t - off] : 0;
            __syncthreads();
            if (t < 128) sc[t] += a;
            __syncthreads();
        }
        const int node0 = bk << 7;
        if (t < 128) {
            const int pc = (cnt[t] + 7) & ~7;
            const int ex = sc[t] - pc;
            cur[t] = ex;
            const int node = node0 + t;
            if (node < N_NODES) {
                const int rs = beg + ex;
                row_start[node] = rs;
                row_end  [node] = min(rs + pc, beg + BCAP);
            }
            const int fb = beg + ex + cnt[t];
            const int fe = min(beg + ex + pc, beg + BCAP);
            for (int i = fb; i < fe; ++i) srcs[i] = ZROW;
        }
        __syncthreads();
        // scatter — batch 4 loads
        for (int i = t; i < n_e; i += 1024) {
            const int p0 = pairs[beg + i];
            const int p1 = (i + 256 < n_e) ? pairs[beg + i + 256] : -1;
            const int p2 = (i + 512 < n_e) ? pairs[beg + i + 512] : -1;
            const int p3 = (i + 768 < n_e) ? pairs[beg + i + 768] : -1;
            { const int r = atomicAdd(&cur[p0 & 127], 1); if (r < BCAP) srcs[beg + r] = p0 >> 7; }
            if (p1 >= 0) { const int r = atomicAdd(&cur[p1 & 127], 1); if (r < BCAP) srcs[beg + r] = p1 >> 7; }
            if (p2 >= 0) { const int r = atomicAdd(&cur[p2 & 127], 1); if (r < BCAP) srcs[beg + r] = p2 >> 7; }
            if (p3 >= 0) { const int r = atomicAdd(&cur[p3 & 127], 1); if (r < BCAP) srcs[beg + r] = p3 >> 7; }
        }
        return;
    }

    // ---------------- in_gemm block (MFMA, register-direct) ----------------
    const int blk  = blockIdx.x - NBUCK;
    const int lane = t & 63;
    const int w    = t >> 6;
    const int tile = blk * 4 + w;
    if (tile >= NTILES_M) return;
    const int quad = lane >> 4;
    const int mrow = lane & 15;
    const int gr   = tile * 16 + mrow;            // < 100000 always (N%16==0)
    const float* xr = x + (size_t)gr * IN_DIM;
    const bf16x8* pb = (const bf16x8*)pWin;

    f32x4 acc0 = {0.f, 0.f, 0.f, 0.f};
    f32x4 acc1 = {0.f, 0.f, 0.f, 0.f};
    f32x4 acc2 = {0.f, 0.f, 0.f, 0.f};
    f32x4 acc3 = {0.f, 0.f, 0.f, 0.f};
    #pragma unroll
    for (int ks = 0; ks < 4; ++ks) {
        const float4 v0 = *(const float4*)(xr + ks * 32 + quad * 8);
        const float4 v1 = *(const float4*)(xr + ks * 32 + quad * 8 + 4);
        union { unsigned u[4]; bf16x8 v; } au;
        au.u[0] = pack2bf(v0.x, v0.y);
        au.u[1] = pack2bf(v0.z, v0.w);
        au.u[2] = pack2bf(v1.x, v1.y);
        au.u[3] = pack2bf(v1.z, v1.w);
        acc0 = __builtin_amdgcn_mfma_f32_16x16x32_bf16(au.v, pb[       ks * 64 + lane], acc0, 0, 0, 0);
        acc1 = __builtin_amdgcn_mfma_f32_16x16x32_bf16(au.v, pb[256 +  ks * 64 + lane], acc1, 0, 0, 0);
        acc2 = __builtin_amdgcn_mfma_f32_16x16x32_bf16(au.v, pb[512 +  ks * 64 + lane], acc2, 0, 0, 0);
        acc3 = __builtin_amdgcn_mfma_f32_16x16x32_bf16(au.v, pb[768 +  ks * 64 + lane], acc3, 0, 0, 0);
    }

    const int colg = lane & 15;
    const int nodeb = tile * 16 + quad * 4;
    const float bv0 = b[     colg];
    const float bv1 = b[16 + colg];
    const float bv2 = b[32 + colg];
    const float bv3 = b[48 + colg];
    #pragma unroll
    for (int r = 0; r < 4; ++r) {
        const size_t ob = (size_t)(nodeb + r) * HID;   // HID bytes per row
        H0[ob      + colg] = f2fp8(fmaxf(acc0[r] + bv0, 0.f));
        H0[ob + 16 + colg] = f2fp8(fmaxf(acc1[r] + bv1, 0.f));
        H0[ob + 32 + colg] = f2fp8(fmaxf(acc2[r] + bv2, 0.f));
        H0[ob + 48 + colg] = f2fp8(fmaxf(acc3[r] + bv3, 0.f));
    }
}

// ---- shared gather phase: fills sup[16][36] with packed-bf16 U rows -------
// 16 lanes per node (2 edge-parity subgroups x 8 chunk lanes x dwordx2).
// H rows are 64 B fp8: half the random-fabric traffic of bf16. Decode via
// HW v_cvt_pk_f32_fp8 (4 cvt + 8 add per 8 elems). Index prefetch rides
// under the H-load latency (R6 structure).
#define ACC8(u) do { \
        dec4((u).x, t0, t1, t2, t3); a0 += t0; a1 += t1; a2 += t2; a3 += t3; \
        dec4((u).y, t0, t1, t2, t3); a4 += t0; a5 += t1; a6 += t2; a7 += t3; } while (0)

#define LOADH(s) (*(const uint2*)(Hin + (size_t)(s) * HID + 8 * fl))

static __device__ __forceinline__ void gather_tile(
    const int* __restrict__ row_start, const int* __restrict__ row_end,
    const int* __restrict__ srcs, const unsigned char* __restrict__ Hin,
    unsigned (*sup)[36], int row0, int t)
{
    const int lane = t & 63;
    const int w    = t >> 6;
    const int nd   = lane >> 4;          // node within wave's group of 4
    const int sub  = (lane >> 3) & 1;    // edge-parity subgroup
    const int fl   = lane & 7;           // 8B chunk within 64B row
    const int node = row0 + (w << 2) + nd;

    const int rs = row_start[node];
    int rem = row_end[node] - rs;        // multiple of 8 (padded with ZROW)
    if (rem < 0) rem = 0;                // bucket-overflow clamp can go negative
    int i = rs + sub;
    const int imax = NBUCK * BCAP - 16;  // safe prefetch base (clamped)

    // self row: independent load, issue before the gather loop
    const uint2 us = LOADH(node);

    // initial index batch (unguarded, address-clamped; values used only
    // when rem >= 8, in which case they are genuine row slots)
    int s0, s1, s2, s3, s4, s5, s6, s7;
    {
        const int ip = min(i, imax);
        s0 = srcs[ip     ]; s1 = srcs[ip +  2];
        s2 = srcs[ip +  4]; s3 = srcs[ip +  6];
        s4 = srcs[ip +  8]; s5 = srcs[ip + 10];
        s6 = srcs[ip + 12]; s7 = srcs[ip + 14];
    }

    float a0 = 0.f, a1 = 0.f, a2 = 0.f, a3 = 0.f;
    float a4 = 0.f, a5 = 0.f, a6 = 0.f, a7 = 0.f;
    float t0, t1, t2, t3;

    for (int nfull = rem >> 4; nfull > 0; --nfull) {
        const uint2 u0 = LOADH(s0); const uint2 u1 = LOADH(s1);
        const uint2 u2 = LOADH(s2); const uint2 u3 = LOADH(s3);
        const uint2 u4 = LOADH(s4); const uint2 u5 = LOADH(s5);
        const uint2 u6 = LOADH(s6); const uint2 u7 = LOADH(s7);
        i += 16;
        const int ip = min(i, imax);     // next-iter (or tail) indices
        const int n0 = srcs[ip     ], n1 = srcs[ip +  2];
        const int n2 = srcs[ip +  4], n3 = srcs[ip +  6];
        const int n4 = srcs[ip +  8], n5 = srcs[ip + 10];
        const int n6 = srcs[ip + 12], n7 = srcs[ip + 14];
        ACC8(u0); ACC8(u1); ACC8(u2); ACC8(u3);
        ACC8(u4); ACC8(u5); ACC8(u6); ACC8(u7);
        s0 = n0; s1 = n1; s2 = n2; s3 = n3;
        s4 = n4; s5 = n5; s6 = n6; s7 = n7;
    }
    if (rem & 8) {
        const uint2 u0 = LOADH(s0); const uint2 u1 = LOADH(s1);
        const uint2 u2 = LOADH(s2); const uint2 u3 = LOADH(s3);
        ACC8(u0); ACC8(u1); ACC8(u2); ACC8(u3);
    }

    // reduce across the two edge-parity subgroups (xor lane bit 3)
    a0 += __shfl_xor(a0, 8, 64); a1 += __shfl_xor(a1, 8, 64);
    a2 += __shfl_xor(a2, 8, 64); a3 += __shfl_xor(a3, 8, 64);
    a4 += __shfl_xor(a4, 8, 64); a5 += __shfl_xor(a5, 8, 64);
    a6 += __shfl_xor(a6, 8, 64); a7 += __shfl_xor(a7, 8, 64);

    // add self row (h + agg)
    ACC8(us);

    // lane fl covers cols 8fl..8fl+7 -> packed bf16 words 4fl..4fl+3
    const int r = (w << 2) + nd;
    if (sub == 0) {
        sup[r][4 * fl    ] = pack2bf(a0, a1);
        sup[r][4 * fl + 1] = pack2bf(a2, a3);
    } else {
        sup[r][4 * fl + 2] = pack2bf(a4, a5);
        sup[r][4 * fl + 3] = pack2bf(a6, a7);
    }
}

// ------- layers 1-2: gather + MFMA layer GEMM, write fp8 Hout --------------
__global__ __launch_bounds__(256) void k_gather_gemm(
    const int* __restrict__ row_start, const int* __restrict__ row_end,
    const int* __restrict__ srcs,
    const unsigned char* __restrict__ Hin, const unsigned* __restrict__ pWl,
    const float* __restrict__ bl, unsigned char* __restrict__ Hout)
{
    __shared__ unsigned sup[16][36];
    const int t = threadIdx.x;
    const int row0 = blockIdx.x * 16;
    gather_tile(row_start, row_end, srcs, Hin, sup, row0, t);
    __syncthreads();

    const int lane = t & 63;
    const int w    = t >> 6;
    const int quad = lane >> 4;
    const int m    = lane & 15;
    const bf16x8* pb = (const bf16x8*)pWl;
    f32x4 acc = {0.f, 0.f, 0.f, 0.f};
    #pragma unroll
    for (int ks = 0; ks < 2; ++ks) {
        const bf16x8 a  = *(const bf16x8*)&sup[m][ks * 16 + quad * 4];
        const bf16x8 bb = pb[((w << 1) + ks) * 64 + lane];
        acc = __builtin_amdgcn_mfma_f32_16x16x32_bf16(a, bb, acc, 0, 0, 0);
    }
    const int jc = w * 16 + m;
    const float bv = bl[jc];
    #pragma unroll
    for (int r = 0; r < 4; ++r) {
        const int node = row0 + quad * 4 + r;
        Hout[(size_t)node * HID + jc] = f2fp8(fmaxf(acc[r] + bv, 0.f));
    }
}

// ------- layer 3 + classifier fused: no H3 global round-trip ---------------
__global__ __launch_bounds__(256) void k_gather_gemm_cls(
    const int* __restrict__ row_start, const int* __restrict__ row_end,
    const int* __restrict__ srcs,
    const unsigned char* __restrict__ Hin, const unsigned* __restrict__ pWl,
    const float* __restrict__ bl, const unsigned* __restrict__ pWc,
    const float* __restrict__ bc, float* __restrict__ out)
{
    __shared__ unsigned sup[16][36];
    __shared__ unsigned short sh2[16][72];   // relu'd H3 tile, bf16
    const int t = threadIdx.x;
    const int row0 = blockIdx.x * 16;
    gather_tile(row_start, row_end, srcs, Hin, sup, row0, t);
    __syncthreads();

    const int lane = t & 63;
    const int w    = t >> 6;
    const int quad = lane >> 4;
    const int m    = lane & 15;
    const bf16x8* pb = (const bf16x8*)pWl;
    f32x4 acc = {0.f, 0.f, 0.f, 0.f};
    #pragma unroll
    for (int ks = 0; ks < 2; ++ks) {
        const bf16x8 a  = *(const bf16x8*)&sup[m][ks * 16 + quad * 4];
        const bf16x8 bb = pb[((w << 1) + ks) * 64 + lane];
        acc = __builtin_amdgcn_mfma_f32_16x16x32_bf16(a, bb, acc, 0, 0, 0);
    }
    const int jc = w * 16 + m;
    const float bv = bl[jc];
    #pragma unroll
    for (int r = 0; r < 4; ++r)
        sh2[quad * 4 + r][jc] = f2bf(fmaxf(acc[r] + bv, 0.f));
    __syncthreads();

    // classifier: waves 0-2 each compute 16 output cols (48 padded >= NCLS)
    if (w < 3) {
        const bf16x8* pbc = (const bf16x8*)pWc;
        f32x4 c = {0.f, 0.f, 0.f, 0.f};
        #pragma unroll
        for (int ks = 0; ks < 2; ++ks) {
            const bf16x8 a = *(const bf16x8*)&sh2[m][ks * 32 + quad * 8];
            c = __builtin_amdgcn_mfma_f32_16x16x32_bf16(a, pbc[(w * 2 + ks) * 64 + lane], c, 0, 0, 0);
        }
        const int col = w * 16 + m;
        if (col < NCLS) {
            const float bcv = bc[col];
            #pragma unroll
            for (int r = 0; r < 4; ++r)
                out[(size_t)(row0 + quad * 4 + r) * NCLS + col] = c[r] + bcv;
        }
    }
}

extern "C" void kernel_launch(void* const* d_in, const int* in_sizes, int n_in,
                              void* d_out, int out_size, void* d_ws, size_t ws_size,
                              hipStream_t stream)
{
    const float* x        = (const float*)d_in[0];
    const int*   ei       = (const int*)  d_in[1];
    const float* W_in     = (const float*)d_in[2];
    const float* b_in     = (const float*)d_in[3];
    const float* W_layers = (const float*)d_in[4];
    const float* b_layers = (const float*)d_in[5];
    const float* W_cls    = (const float*)d_in[6];
    const float* b_cls    = (const float*)d_in[7];
    float* out = (float*)d_out;

    // ws layout (~32 MB): H0/H1 (fp8, 6.4 MB each), build scratch, weights
    unsigned char* H0 = (unsigned char*)d_ws;
    unsigned char* H1 = H0 + (size_t)(N_NODES + 1) * HID;
    int* wsp       = (int*)(H1 + (size_t)(N_NODES + 1) * HID);
    int* pairs     = wsp;                         // NBUCK*BCAP = 2.40M ints
    int* srcs      = wsp + NBUCK * BCAP;          // 2.40M ints
    int* row_start = wsp + 2 * NBUCK * BCAP;      // 100000 (pad 100096)
    int* row_end   = row_start + 100096;          // 100000
    int* cursor    = row_end + 100096;            // 782 (pad 1024)
    unsigned* pWin = (unsigned*)(cursor + 1024);  // 4096
    unsigned* pWl  = pWin + 4096;                 // 6144 (3 layers x 2048)
    unsigned* pWc  = pWl + 6144;                  // 1536

    hipMemsetAsync(cursor, 0, 1024 * sizeof(int), stream);

    k_part_prep<<<NTILE + PREP_BLKS, 512, 0, stream>>>(
        ei, cursor, pairs, W_in, W_layers, W_cls, pWin, pWl, pWc, H0, H1);

    k_bsort_ingemm<<<NBUCK + IN_BLOCKS, 256, 0, stream>>>(
        cursor, pairs, srcs, row_start, row_end, x, pWin, b_in, H0);

    const int gemm_blocks = N_NODES / 16;         // 6250 (gather)
    k_gather_gemm<<<gemm_blocks, 256, 0, stream>>>(
        row_start, row_end, srcs, H0, pWl,          b_layers,        H1);
    k_gather_gemm<<<gemm_blocks, 256, 0, stream>>>(
        row_start, row_end, srcs, H1, pWl + 2048,   b_layers + HID,  H0);
    k_gather_gemm_cls<<<gemm_blocks, 256, 0, stream>>>(
        row_start, row_end, srcs, H0, pWl + 4096,   b_layers + 2*HID,
        pWc, b_cls, out);
}